// Round 1
// baseline (193.935 us; speedup 1.0000x reference)
//
#include <hip/hip_runtime.h>
#include <hip/hip_fp16.h>

typedef _Float16 f16x8 __attribute__((ext_vector_type(8)));
typedef _Float16 f16x4 __attribute__((ext_vector_type(4)));
typedef float    f32x4 __attribute__((ext_vector_type(4)));

#define NB   32
#define SEQ  1024
#define EDIM 768
#define HD   64
#define MTOT (NB * SEQ)

// ---------------- kernel 0: pack weights -> Wt fp16 [192][768], Wt[c][e] = W[e][c] ----
__global__ __launch_bounds__(256) void pack_w(const float* __restrict__ Wq,
                                              const float* __restrict__ Wk,
                                              const float* __restrict__ Wv,
                                              _Float16* __restrict__ Wt) {
    int c = blockIdx.x;  // 0..191
    const float* src = (c < 64) ? Wq : (c < 128) ? Wk : Wv;
    int cc = c & 63;
    for (int e = threadIdx.x; e < EDIM; e += 256)
        Wt[(size_t)c * EDIM + e] = (_Float16)src[(size_t)e * HD + cc];
}

// ---------------- kernel 1: QKV projection, 128x192 tile, fp16 MFMA ----------------
__global__ __launch_bounds__(256) void proj_kernel(const float* __restrict__ x,
                                                   const _Float16* __restrict__ Wt,
                                                   float* __restrict__ qb,
                                                   float* __restrict__ kb,
                                                   float* __restrict__ vb) {
    __shared__ _Float16 xs[128][72];    // +8 pad: 2-way LDS aliasing only (free)
    __shared__ _Float16 wsh[192][72];
    const int tid  = threadIdx.x;
    const int wave = tid >> 6, lane = tid & 63;
    const int lr = lane & 15, lk = (lane >> 4) * 8, lrow = (lane >> 4) * 4;
    const int m0 = blockIdx.x * 128;

    f32x4 acc[2][12] = {};

    for (int kt = 0; kt < EDIM / 64; ++kt) {
        const int e0 = kt * 64;
        // stage x tile [128][64] -> fp16 LDS (coalesced float4 reads)
        for (int i = 0; i < 8; ++i) {
            int lin = tid + i * 256;            // float4 units, 2048 total
            int r = lin >> 4, c4 = (lin & 15) * 4;
            f32x4 v = *(const f32x4*)&x[(size_t)(m0 + r) * EDIM + e0 + c4];
            f16x4 h;
            h[0] = (_Float16)v[0]; h[1] = (_Float16)v[1];
            h[2] = (_Float16)v[2]; h[3] = (_Float16)v[3];
            *(f16x4*)&xs[r][c4] = h;
        }
        // stage Wt tile [192][64] (already fp16, contiguous 16B chunks)
        for (int i = 0; i < 6; ++i) {
            int lin = tid + i * 256;            // 8-half chunks, 1536 total
            int c = lin >> 3, c8 = (lin & 7) * 8;
            *(f16x8*)&wsh[c][c8] = *(const f16x8*)&Wt[(size_t)c * EDIM + e0 + c8];
        }
        __syncthreads();

        f16x8 a0  = *(const f16x8*)&xs[wave * 32 + lr][lk];
        f16x8 a1  = *(const f16x8*)&xs[wave * 32 + 16 + lr][lk];
        f16x8 a0b = *(const f16x8*)&xs[wave * 32 + lr][32 + lk];
        f16x8 a1b = *(const f16x8*)&xs[wave * 32 + 16 + lr][32 + lk];
        for (int nb = 0; nb < 12; ++nb) {
            f16x8 b0 = *(const f16x8*)&wsh[nb * 16 + lr][lk];
            f16x8 b1 = *(const f16x8*)&wsh[nb * 16 + lr][32 + lk];
            acc[0][nb] = __builtin_amdgcn_mfma_f32_16x16x32_f16(a0,  b0, acc[0][nb], 0, 0, 0);
            acc[1][nb] = __builtin_amdgcn_mfma_f32_16x16x32_f16(a1,  b0, acc[1][nb], 0, 0, 0);
            acc[0][nb] = __builtin_amdgcn_mfma_f32_16x16x32_f16(a0b, b1, acc[0][nb], 0, 0, 0);
            acc[1][nb] = __builtin_amdgcn_mfma_f32_16x16x32_f16(a1b, b1, acc[1][nb], 0, 0, 0);
        }
        __syncthreads();
    }
    // epilogue: D layout col=lane&15, row=(lane>>4)*4+j
    for (int rb = 0; rb < 2; ++rb) {
        int row = m0 + wave * 32 + rb * 16 + lrow;
        for (int nb = 0; nb < 12; ++nb) {
            float* dst = (nb < 4) ? qb : (nb < 8) ? kb : vb;
            int lc = (nb & 3) * 16 + lr;
            for (int j = 0; j < 4; ++j)
                dst[(size_t)(row + j) * HD + lc] = acc[rb][nb][j];
        }
    }
}

// ---------------- kernel 2: per-batch LN stats (mean, rstd) for Q,K,V -------------
__global__ __launch_bounds__(256) void stats_kernel(const float* __restrict__ qb,
                                                    const float* __restrict__ kb,
                                                    const float* __restrict__ vb,
                                                    float* __restrict__ stats) {
    __shared__ double ss[4], sq2[4];
    int b = blockIdx.x, tid = threadIdx.x;
    const float* arrs[3] = {qb, kb, vb};
    for (int a = 0; a < 3; ++a) {
        const float* p = arrs[a] + (size_t)b * (SEQ * HD);
        double s = 0.0, q = 0.0;
        for (int i = tid * 4; i < SEQ * HD; i += 1024) {
            f32x4 v = *(const f32x4*)&p[i];
            for (int j = 0; j < 4; ++j) { double d = v[j]; s += d; q += d * d; }
        }
        for (int off = 32; off > 0; off >>= 1) {
            s += __shfl_down(s, off);
            q += __shfl_down(q, off);
        }
        if ((tid & 63) == 0) { ss[tid >> 6] = s; sq2[tid >> 6] = q; }
        __syncthreads();
        if (tid == 0) {
            double S1 = ss[0] + ss[1] + ss[2] + ss[3];
            double S2 = sq2[0] + sq2[1] + sq2[2] + sq2[3];
            double mean = S1 / (double)(SEQ * HD);
            double var  = S2 / (double)(SEQ * HD) - mean * mean;
            stats[b * 6 + a * 2 + 0] = (float)mean;
            stats[b * 6 + a * 2 + 1] = (float)(1.0 / sqrt(var + 1e-5));
        }
        __syncthreads();
    }
}

// ---------------- kernel 3: flash attention, fp16 MFMA, online softmax ------------
__global__ __launch_bounds__(256) void attn_kernel(const float* __restrict__ qbuf,
                                                   const float* __restrict__ kbuf,
                                                   const float* __restrict__ vbuf,
                                                   const float* __restrict__ stats,
                                                   float* __restrict__ out) {
    __shared__ _Float16 ksm[64][72];      // K tile [kv][d]
    __shared__ _Float16 vsm[64][72];      // V tile transposed: vsm[d][kv]
    __shared__ _Float16 psm[4][32][72];   // per-wave P tile [qrow][kv]
    const int b = blockIdx.x >> 3, qt = blockIdx.x & 7;
    const int tid = threadIdx.x, wave = tid >> 6, lane = tid & 63;
    const int lr = lane & 15, lk = (lane >> 4) * 8, lrow = (lane >> 4) * 4;
    const float mq = stats[b * 6 + 0], rq = stats[b * 6 + 1];
    const float mk = stats[b * 6 + 2], rk = stats[b * 6 + 3];
    const float mv = stats[b * 6 + 4], rv = stats[b * 6 + 5];
    const float* Q = qbuf + (size_t)b * (SEQ * HD);
    const float* K = kbuf + (size_t)b * (SEQ * HD);
    const float* V = vbuf + (size_t)b * (SEQ * HD);
    const int q0 = qt * 128 + wave * 32;
    const float qs = rq * 0.125f;   // fold 1/sqrt(64) into normalized Q

    // Q fragments in registers (A layout: row=lane&15, k=(lane>>4)*8+j)
    f16x8 aq[2][2];
    for (int rb = 0; rb < 2; ++rb) {
        int row = q0 + rb * 16 + lr;
        for (int kb2 = 0; kb2 < 2; ++kb2) {
            int d0 = kb2 * 32 + lk;
            f32x4 v1 = *(const f32x4*)&Q[(size_t)row * HD + d0];
            f32x4 v2 = *(const f32x4*)&Q[(size_t)row * HD + d0 + 4];
            f16x8 f;
            f[0] = (_Float16)((v1[0] - mq) * qs); f[1] = (_Float16)((v1[1] - mq) * qs);
            f[2] = (_Float16)((v1[2] - mq) * qs); f[3] = (_Float16)((v1[3] - mq) * qs);
            f[4] = (_Float16)((v2[0] - mq) * qs); f[5] = (_Float16)((v2[1] - mq) * qs);
            f[6] = (_Float16)((v2[2] - mq) * qs); f[7] = (_Float16)((v2[3] - mq) * qs);
            aq[rb][kb2] = f;
        }
    }

    f32x4 o[2][4] = {};
    float mrow[2][4], lsum[2][4];
    for (int rb = 0; rb < 2; ++rb)
        for (int j = 0; j < 4; ++j) { mrow[rb][j] = -1e30f; lsum[rb][j] = 0.f; }

    for (int kv0 = 0; kv0 < SEQ; kv0 += 64) {
        // stage K (row-major) and V (transposed) as normalized fp16
        for (int i = 0; i < 4; ++i) {
            int lin = tid + i * 256;
            int r = lin >> 4, c4 = (lin & 15) * 4;
            f32x4 kv = *(const f32x4*)&K[(size_t)(kv0 + r) * HD + c4];
            f16x4 h;
            h[0] = (_Float16)((kv[0] - mk) * rk); h[1] = (_Float16)((kv[1] - mk) * rk);
            h[2] = (_Float16)((kv[2] - mk) * rk); h[3] = (_Float16)((kv[3] - mk) * rk);
            *(f16x4*)&ksm[r][c4] = h;
            f32x4 vv = *(const f32x4*)&V[(size_t)(kv0 + r) * HD + c4];
            vsm[c4 + 0][r] = (_Float16)((vv[0] - mv) * rv);
            vsm[c4 + 1][r] = (_Float16)((vv[1] - mv) * rv);
            vsm[c4 + 2][r] = (_Float16)((vv[2] - mv) * rv);
            vsm[c4 + 3][r] = (_Float16)((vv[3] - mv) * rv);
        }
        __syncthreads();

        // S = (Qn/8) * Kn^T   (D: row=q, col=kv)
        f32x4 sa[2][4] = {};
        for (int kb2 = 0; kb2 < 2; ++kb2) {
            for (int cb = 0; cb < 4; ++cb) {
                f16x8 bk = *(const f16x8*)&ksm[cb * 16 + lr][kb2 * 32 + lk];
                sa[0][cb] = __builtin_amdgcn_mfma_f32_16x16x32_f16(aq[0][kb2], bk, sa[0][cb], 0, 0, 0);
                sa[1][cb] = __builtin_amdgcn_mfma_f32_16x16x32_f16(aq[1][kb2], bk, sa[1][cb], 0, 0, 0);
            }
        }

        // online softmax (row lives across 16 lanes sharing lane>>4)
        for (int rb = 0; rb < 2; ++rb) {
            for (int j = 0; j < 4; ++j) {
                float pm = fmaxf(fmaxf(sa[rb][0][j], sa[rb][1][j]),
                                 fmaxf(sa[rb][2][j], sa[rb][3][j]));
                pm = fmaxf(pm, __shfl_xor(pm, 1));
                pm = fmaxf(pm, __shfl_xor(pm, 2));
                pm = fmaxf(pm, __shfl_xor(pm, 4));
                pm = fmaxf(pm, __shfl_xor(pm, 8));
                float mnew  = fmaxf(mrow[rb][j], pm);
                float alpha = __expf(mrow[rb][j] - mnew);
                mrow[rb][j] = mnew;
                float rs = 0.f;
                for (int cb = 0; cb < 4; ++cb) {
                    float p = __expf(sa[rb][cb][j] - mnew);
                    sa[rb][cb][j] = p;
                    rs += p;
                }
                rs += __shfl_xor(rs, 1); rs += __shfl_xor(rs, 2);
                rs += __shfl_xor(rs, 4); rs += __shfl_xor(rs, 8);
                lsum[rb][j] = lsum[rb][j] * alpha + rs;
                o[rb][0][j] *= alpha; o[rb][1][j] *= alpha;
                o[rb][2][j] *= alpha; o[rb][3][j] *= alpha;
            }
            for (int cb = 0; cb < 4; ++cb)
                for (int j = 0; j < 4; ++j)
                    psm[wave][rb * 16 + lrow + j][cb * 16 + lr] = (_Float16)sa[rb][cb][j];
        }
        __syncthreads();

        // O += P * V
        for (int kvb = 0; kvb < 2; ++kvb) {
            f16x8 pa0 = *(const f16x8*)&psm[wave][lr][kvb * 32 + lk];
            f16x8 pa1 = *(const f16x8*)&psm[wave][16 + lr][kvb * 32 + lk];
            for (int db = 0; db < 4; ++db) {
                f16x8 bv = *(const f16x8*)&vsm[db * 16 + lr][kvb * 32 + lk];
                o[0][db] = __builtin_amdgcn_mfma_f32_16x16x32_f16(pa0, bv, o[0][db], 0, 0, 0);
                o[1][db] = __builtin_amdgcn_mfma_f32_16x16x32_f16(pa1, bv, o[1][db], 0, 0, 0);
            }
        }
        __syncthreads();
    }

    for (int rb = 0; rb < 2; ++rb) {
        for (int j = 0; j < 4; ++j) {
            float inv = 1.f / lsum[rb][j];
            size_t row = (size_t)b * SEQ + q0 + rb * 16 + lrow + j;
            for (int db = 0; db < 4; ++db)
                out[row * HD + db * 16 + lr] = o[rb][db][j] * inv;
        }
    }
}

extern "C" void kernel_launch(void* const* d_in, const int* in_sizes, int n_in,
                              void* d_out, int out_size, void* d_ws, size_t ws_size,
                              hipStream_t stream) {
    const float* x  = (const float*)d_in[0];
    const float* Wq = (const float*)d_in[1];
    const float* Wk = (const float*)d_in[2];
    const float* Wv = (const float*)d_in[3];
    float* out = (float*)d_out;
    char* ws = (char*)d_ws;

    _Float16* Wt  = (_Float16*)ws;                       // 192*768*2 = 294912 B
    float* stats  = (float*)(ws + 0x80000);              // 768 B
    float* qb     = (float*)(ws + 0x100000);             // 8 MiB each
    float* kb     = (float*)(ws + 0x100000 + 8388608);
    float* vb     = (float*)(ws + 0x100000 + 2 * 8388608);

    pack_w<<<192, 256, 0, stream>>>(Wq, Wk, Wv, Wt);
    proj_kernel<<<MTOT / 128, 256, 0, stream>>>(x, Wt, qb, kb, vb);
    stats_kernel<<<NB, 256, 0, stream>>>(qb, kb, vb, stats);
    attn_kernel<<<NB * 8, 256, 0, stream>>>(qb, kb, vb, stats, out);
}

// Round 2
// 100.540 us; speedup vs baseline: 1.9289x; 1.9289x over previous
//
#include <hip/hip_runtime.h>
#include <hip/hip_fp16.h>

typedef _Float16 f16x8 __attribute__((ext_vector_type(8)));
typedef _Float16 f16x4 __attribute__((ext_vector_type(4)));
typedef float    f32x4 __attribute__((ext_vector_type(4)));

#define NB   32
#define SEQ  1024
#define EDIM 768
#define HD   64
#define MTOT (NB * SEQ)

// ---------------- kernel 0: pack weights -> Wt fp16 [192][768], Wt[c][e] = W[e][c] ----
__global__ __launch_bounds__(256) void pack_w(const float* __restrict__ Wq,
                                              const float* __restrict__ Wk,
                                              const float* __restrict__ Wv,
                                              _Float16* __restrict__ Wt) {
    int c = blockIdx.x;  // 0..191
    const float* src = (c < 64) ? Wq : (c < 128) ? Wk : Wv;
    int cc = c & 63;
    for (int e = threadIdx.x; e < EDIM; e += 256)
        Wt[(size_t)c * EDIM + e] = (_Float16)src[(size_t)e * HD + cc];
}

// ---------------- kernel 1: QKV projection, 128x192 tile, fp16 MFMA, fp16 out -------
__global__ __launch_bounds__(256) void proj_kernel(const float* __restrict__ x,
                                                   const _Float16* __restrict__ Wt,
                                                   _Float16* __restrict__ q16,
                                                   _Float16* __restrict__ k16,
                                                   _Float16* __restrict__ v16) {
    __shared__ _Float16 xs[128][72];
    __shared__ _Float16 wsh[192][72];
    const int tid  = threadIdx.x;
    const int wave = tid >> 6, lane = tid & 63;
    const int lr = lane & 15, lk = (lane >> 4) * 8, lrow = (lane >> 4) * 4;
    const int m0 = blockIdx.x * 128;

    f32x4 acc[2][12] = {};

    for (int kt = 0; kt < EDIM / 64; ++kt) {
        const int e0 = kt * 64;
        for (int i = 0; i < 8; ++i) {
            int lin = tid + i * 256;
            int r = lin >> 4, c4 = (lin & 15) * 4;
            f32x4 v = *(const f32x4*)&x[(size_t)(m0 + r) * EDIM + e0 + c4];
            f16x4 h;
            h[0] = (_Float16)v[0]; h[1] = (_Float16)v[1];
            h[2] = (_Float16)v[2]; h[3] = (_Float16)v[3];
            *(f16x4*)&xs[r][c4] = h;
        }
        for (int i = 0; i < 6; ++i) {
            int lin = tid + i * 256;
            int c = lin >> 3, c8 = (lin & 7) * 8;
            *(f16x8*)&wsh[c][c8] = *(const f16x8*)&Wt[(size_t)c * EDIM + e0 + c8];
        }
        __syncthreads();

        f16x8 a0  = *(const f16x8*)&xs[wave * 32 + lr][lk];
        f16x8 a1  = *(const f16x8*)&xs[wave * 32 + 16 + lr][lk];
        f16x8 a0b = *(const f16x8*)&xs[wave * 32 + lr][32 + lk];
        f16x8 a1b = *(const f16x8*)&xs[wave * 32 + 16 + lr][32 + lk];
        for (int nb = 0; nb < 12; ++nb) {
            f16x8 b0 = *(const f16x8*)&wsh[nb * 16 + lr][lk];
            f16x8 b1 = *(const f16x8*)&wsh[nb * 16 + lr][32 + lk];
            acc[0][nb] = __builtin_amdgcn_mfma_f32_16x16x32_f16(a0,  b0, acc[0][nb], 0, 0, 0);
            acc[1][nb] = __builtin_amdgcn_mfma_f32_16x16x32_f16(a1,  b0, acc[1][nb], 0, 0, 0);
            acc[0][nb] = __builtin_amdgcn_mfma_f32_16x16x32_f16(a0b, b1, acc[0][nb], 0, 0, 0);
            acc[1][nb] = __builtin_amdgcn_mfma_f32_16x16x32_f16(a1b, b1, acc[1][nb], 0, 0, 0);
        }
        __syncthreads();
    }
    for (int rb = 0; rb < 2; ++rb) {
        int row = m0 + wave * 32 + rb * 16 + lrow;
        for (int nb = 0; nb < 12; ++nb) {
            _Float16* dst = (nb < 4) ? q16 : (nb < 8) ? k16 : v16;
            int lc = (nb & 3) * 16 + lr;
            for (int j = 0; j < 4; ++j)
                dst[(size_t)(row + j) * HD + lc] = (_Float16)acc[rb][nb][j];
        }
    }
}

// ---------------- kernel 2: per-(batch,tensor) LN stats: mean, rstd ----------------
__global__ __launch_bounds__(256) void stats_kernel(const _Float16* __restrict__ q16,
                                                    const _Float16* __restrict__ k16,
                                                    const _Float16* __restrict__ v16,
                                                    float* __restrict__ stats) {
    __shared__ double ss[4], sq2[4];
    int b = blockIdx.x / 3, a = blockIdx.x % 3, tid = threadIdx.x;
    const _Float16* arrs[3] = {q16, k16, v16};
    const _Float16* p = arrs[a] + (size_t)b * (SEQ * HD);
    float s = 0.f, q = 0.f;
    for (int i = tid * 8; i < SEQ * HD; i += 2048) {
        f16x8 v = *(const f16x8*)&p[i];
        for (int j = 0; j < 8; ++j) { float d = (float)v[j]; s += d; q += d * d; }
    }
    double sd = s, qd = q;
    for (int off = 32; off > 0; off >>= 1) {
        sd += __shfl_down(sd, off);
        qd += __shfl_down(qd, off);
    }
    if ((tid & 63) == 0) { ss[tid >> 6] = sd; sq2[tid >> 6] = qd; }
    __syncthreads();
    if (tid == 0) {
        double S1 = ss[0] + ss[1] + ss[2] + ss[3];
        double S2 = sq2[0] + sq2[1] + sq2[2] + sq2[3];
        double mean = S1 / (double)(SEQ * HD);
        double var  = S2 / (double)(SEQ * HD) - mean * mean;
        stats[b * 8 + a * 2 + 0] = (float)mean;
        stats[b * 8 + a * 2 + 1] = (float)(1.0 / sqrt(var + 1e-5));
    }
}

// ---------------- kernel 2b: per-kv-column score adjustment --------------------------
// skadj[b][s] = (rq*rk/8) * mq * sum_d k16[b][s][d]
__global__ __launch_bounds__(256) void skadj_kernel(const _Float16* __restrict__ k16,
                                                    const float* __restrict__ stats,
                                                    float* __restrict__ skadj) {
    int b = blockIdx.x >> 2, part = blockIdx.x & 3;
    int r = part * 256 + threadIdx.x;
    const float mq = stats[b * 8 + 0], rq = stats[b * 8 + 1], rk = stats[b * 8 + 3];
    const _Float16* p = k16 + ((size_t)b * SEQ + r) * HD;
    float s = 0.f;
    for (int i = 0; i < 8; ++i) {
        f16x8 v = *(const f16x8*)&p[i * 8];
        for (int j = 0; j < 8; ++j) s += (float)v[j];
    }
    skadj[b * SEQ + r] = rq * rk * 0.125f * mq * s;
}

// ---------------- kernel 2c: transpose V -> v16t [B][64][1024] ----------------------
__global__ __launch_bounds__(256) void transpose_v(const _Float16* __restrict__ v16,
                                                   _Float16* __restrict__ v16t) {
    __shared__ _Float16 t[64][72];
    int b = blockIdx.x >> 4, s0 = (blockIdx.x & 15) * 64;
    int tid = threadIdx.x;
    for (int i = 0; i < 2; ++i) {
        int lin = tid + i * 256;
        int s = lin >> 3, d8 = (lin & 7) * 8;
        *(f16x8*)&t[s][d8] = *(const f16x8*)&v16[((size_t)b * SEQ + s0 + s) * HD + d8];
    }
    __syncthreads();
    for (int i = 0; i < 2; ++i) {
        int lin = tid + i * 256;
        int d = lin >> 3, s8 = (lin & 7) * 8;
        f16x8 g;
        for (int k = 0; k < 8; ++k) g[k] = t[s8 + k][d];
        *(f16x8*)&v16t[((size_t)b * HD + d) * SEQ + s0 + s8] = g;
    }
}

// ---------------- kernel 3: flash attention, raw fp16 + folded LN -------------------
__global__ __launch_bounds__(256) void attn_kernel(const _Float16* __restrict__ q16,
                                                   const _Float16* __restrict__ k16,
                                                   const _Float16* __restrict__ v16t,
                                                   const float* __restrict__ stats,
                                                   const float* __restrict__ skadj,
                                                   float* __restrict__ out) {
    __shared__ _Float16 ksm[64][72];
    __shared__ _Float16 vsm[64][72];     // [d][kv]
    __shared__ _Float16 psm[4][16][72];  // per-wave, no barrier needed
    const int b = blockIdx.x >> 4, qt = blockIdx.x & 15;
    const int tid = threadIdx.x, wave = tid >> 6, lane = tid & 63;
    const int lr = lane & 15, lk = (lane >> 4) * 8, lrow = (lane >> 4) * 4;
    const float sscale = stats[b * 8 + 1] * stats[b * 8 + 3] * 0.125f;
    const float mv = stats[b * 8 + 4], rv = stats[b * 8 + 5];
    const int q0 = qt * 64 + wave * 16;
    const _Float16* Qb = q16 + ((size_t)b * SEQ + q0) * HD;
    const float* adjb = skadj + b * SEQ;

    f16x8 aq0 = *(const f16x8*)&Qb[(size_t)lr * HD + lk];
    f16x8 aq1 = *(const f16x8*)&Qb[(size_t)lr * HD + 32 + lk];

    f32x4 o[4] = {};
    float mrow[4], lsum[4];
    for (int j = 0; j < 4; ++j) { mrow[j] = -1e30f; lsum[j] = 0.f; }

    for (int kv0 = 0; kv0 < SEQ; kv0 += 64) {
        // stage K tile [kv][d] and V^T tile [d][kv] (pure fp16 copies)
        for (int i = 0; i < 2; ++i) {
            int lin = tid + i * 256;
            int r = lin >> 3, c = (lin & 7) * 8;
            *(f16x8*)&ksm[r][c] = *(const f16x8*)&k16[((size_t)b * SEQ + kv0 + r) * HD + c];
        }
        for (int i = 0; i < 2; ++i) {
            int lin = tid + i * 256;
            int d = lin >> 3, c = (lin & 7) * 8;
            *(f16x8*)&vsm[d][c] = *(const f16x8*)&v16t[((size_t)b * HD + d) * SEQ + kv0 + c];
        }
        __syncthreads();

        // S_raw = Q_raw * K_raw^T
        f32x4 sa[4];
        float adjv[4];
        for (int cb = 0; cb < 4; ++cb) {
            sa[cb] = (f32x4){0.f, 0.f, 0.f, 0.f};
            f16x8 bk0 = *(const f16x8*)&ksm[cb * 16 + lr][lk];
            f16x8 bk1 = *(const f16x8*)&ksm[cb * 16 + lr][32 + lk];
            sa[cb] = __builtin_amdgcn_mfma_f32_16x16x32_f16(aq0, bk0, sa[cb], 0, 0, 0);
            sa[cb] = __builtin_amdgcn_mfma_f32_16x16x32_f16(aq1, bk1, sa[cb], 0, 0, 0);
            adjv[cb] = adjb[kv0 + cb * 16 + lr];
        }

        // online softmax (16 lanes per row, shfl-xor tree)
        for (int j = 0; j < 4; ++j) {
            float sv0 = sa[0][j] * sscale - adjv[0];
            float sv1 = sa[1][j] * sscale - adjv[1];
            float sv2 = sa[2][j] * sscale - adjv[2];
            float sv3 = sa[3][j] * sscale - adjv[3];
            float pm = fmaxf(fmaxf(sv0, sv1), fmaxf(sv2, sv3));
            pm = fmaxf(pm, __shfl_xor(pm, 1));
            pm = fmaxf(pm, __shfl_xor(pm, 2));
            pm = fmaxf(pm, __shfl_xor(pm, 4));
            pm = fmaxf(pm, __shfl_xor(pm, 8));
            float mnew  = fmaxf(mrow[j], pm);
            float alpha = __expf(mrow[j] - mnew);
            mrow[j] = mnew;
            float p0 = __expf(sv0 - mnew), p1 = __expf(sv1 - mnew);
            float p2 = __expf(sv2 - mnew), p3 = __expf(sv3 - mnew);
            sa[0][j] = p0; sa[1][j] = p1; sa[2][j] = p2; sa[3][j] = p3;
            float rs = (p0 + p1) + (p2 + p3);
            rs += __shfl_xor(rs, 1); rs += __shfl_xor(rs, 2);
            rs += __shfl_xor(rs, 4); rs += __shfl_xor(rs, 8);
            lsum[j] = lsum[j] * alpha + rs;
            o[0][j] *= alpha; o[1][j] *= alpha; o[2][j] *= alpha; o[3][j] *= alpha;
        }
        for (int cb = 0; cb < 4; ++cb)
            for (int j = 0; j < 4; ++j)
                psm[wave][lrow + j][cb * 16 + lr] = (_Float16)sa[cb][j];
        // same-wave LDS write->read: ordered by lgkmcnt, no barrier

        f16x8 pa0 = *(const f16x8*)&psm[wave][lr][lk];
        f16x8 pa1 = *(const f16x8*)&psm[wave][lr][32 + lk];
        for (int db = 0; db < 4; ++db) {
            f16x8 bv0 = *(const f16x8*)&vsm[db * 16 + lr][lk];
            f16x8 bv1 = *(const f16x8*)&vsm[db * 16 + lr][32 + lk];
            o[db] = __builtin_amdgcn_mfma_f32_16x16x32_f16(pa0, bv0, o[db], 0, 0, 0);
            o[db] = __builtin_amdgcn_mfma_f32_16x16x32_f16(pa1, bv1, o[db], 0, 0, 0);
        }
        __syncthreads();
    }

    for (int j = 0; j < 4; ++j) {
        float inv = 1.f / lsum[j];
        size_t row = (size_t)b * SEQ + q0 + lrow + j;
        for (int db = 0; db < 4; ++db)
            out[row * HD + db * 16 + lr] = rv * (o[db][j] * inv - mv);
    }
}

extern "C" void kernel_launch(void* const* d_in, const int* in_sizes, int n_in,
                              void* d_out, int out_size, void* d_ws, size_t ws_size,
                              hipStream_t stream) {
    const float* x  = (const float*)d_in[0];
    const float* Wq = (const float*)d_in[1];
    const float* Wk = (const float*)d_in[2];
    const float* Wv = (const float*)d_in[3];
    float* out = (float*)d_out;
    char* ws = (char*)d_ws;

    _Float16* Wt   = (_Float16*)ws;                 // 294912 B
    float* stats   = (float*)(ws + 0x50000);        // 32*8*4 = 1 KB
    float* skadj   = (float*)(ws + 0x51000);        // 32*1024*4 = 128 KB
    _Float16* q16  = (_Float16*)(ws + 0x100000);    // 4 MiB each
    _Float16* k16  = (_Float16*)(ws + 0x500000);
    _Float16* v16  = (_Float16*)(ws + 0x900000);
    _Float16* v16t = (_Float16*)(ws + 0xD00000);

    pack_w<<<192, 256, 0, stream>>>(Wq, Wk, Wv, Wt);
    proj_kernel<<<MTOT / 128, 256, 0, stream>>>(x, Wt, q16, k16, v16);
    stats_kernel<<<NB * 3, 256, 0, stream>>>(q16, k16, v16, stats);
    skadj_kernel<<<NB * 4, 256, 0, stream>>>(k16, stats, skadj);
    transpose_v<<<NB * 16, 256, 0, stream>>>(v16, v16t);
    attn_kernel<<<NB * 16, 256, 0, stream>>>(q16, k16, v16t, stats, skadj, out);
}

// Round 3
// 77.209 us; speedup vs baseline: 2.5118x; 1.3022x over previous
//
#include <hip/hip_runtime.h>
#include <hip/hip_fp16.h>

typedef _Float16 f16x8 __attribute__((ext_vector_type(8)));
typedef _Float16 f16x4 __attribute__((ext_vector_type(4)));
typedef float    f32x4 __attribute__((ext_vector_type(4)));

#define NB   32
#define SEQ  1024
#define EDIM 768
#define HD   64
#define MTOT (NB * SEQ)

// ---------------- kernel 0: pack weights -> Wt fp16 [192][768], Wt[c][e] = W[e][c] ----
__global__ __launch_bounds__(256) void pack_w(const float* __restrict__ Wq,
                                              const float* __restrict__ Wk,
                                              const float* __restrict__ Wv,
                                              _Float16* __restrict__ Wt) {
    int c = blockIdx.x;  // 0..191
    const float* src = (c < 64) ? Wq : (c < 128) ? Wk : Wv;
    int cc = c & 63;
    for (int e = threadIdx.x; e < EDIM; e += 256)
        Wt[(size_t)c * EDIM + e] = (_Float16)src[(size_t)e * HD + cc];
}

// ---------------- kernel 1: QKV projection, 64x192 tile, double-buffered prefetch ----
// Also emits: per-block LN partials (sum, sumsq per tensor) and per-row K sums.
__global__ __launch_bounds__(256) void proj_kernel(const float* __restrict__ x,
                                                   const _Float16* __restrict__ Wt,
                                                   _Float16* __restrict__ q16,
                                                   _Float16* __restrict__ k16,
                                                   _Float16* __restrict__ v16,
                                                   float* __restrict__ part,
                                                   float* __restrict__ ksum) {
    __shared__ _Float16 xs[2][64][72];
    __shared__ _Float16 wsh[2][192][72];
    __shared__ float red[4][6];
    const int tid  = threadIdx.x;
    const int wave = tid >> 6, lane = tid & 63;
    const int lr = lane & 15, lk = (lane >> 4) * 8, lrow = (lane >> 4) * 4;
    const int m0 = blockIdx.x * 64;

    f32x4 acc[12] = {};
    f32x4 xv[4];
    f16x8 wv[6];

    // prologue: load + stage tile 0
    #pragma unroll
    for (int i = 0; i < 4; ++i) {
        int lin = tid + i * 256, r = lin >> 4, c4 = (lin & 15) * 4;
        xv[i] = *(const f32x4*)&x[(size_t)(m0 + r) * EDIM + c4];
    }
    #pragma unroll
    for (int i = 0; i < 6; ++i) {
        int lin = tid + i * 256, c = lin >> 3, c8 = (lin & 7) * 8;
        wv[i] = *(const f16x8*)&Wt[(size_t)c * EDIM + c8];
    }
    #pragma unroll
    for (int i = 0; i < 4; ++i) {
        int lin = tid + i * 256, r = lin >> 4, c4 = (lin & 15) * 4;
        f16x4 h;
        h[0] = (_Float16)xv[i][0]; h[1] = (_Float16)xv[i][1];
        h[2] = (_Float16)xv[i][2]; h[3] = (_Float16)xv[i][3];
        *(f16x4*)&xs[0][r][c4] = h;
    }
    #pragma unroll
    for (int i = 0; i < 6; ++i) {
        int lin = tid + i * 256, c = lin >> 3, c8 = (lin & 7) * 8;
        *(f16x8*)&wsh[0][c][c8] = wv[i];
    }
    __syncthreads();

    for (int kt = 0; kt < 12; ++kt) {
        const int cur = kt & 1;
        if (kt < 11) {   // issue next-tile loads EARLY (latency hides under MFMA)
            const int e0 = (kt + 1) * 64;
            #pragma unroll
            for (int i = 0; i < 4; ++i) {
                int lin = tid + i * 256, r = lin >> 4, c4 = (lin & 15) * 4;
                xv[i] = *(const f32x4*)&x[(size_t)(m0 + r) * EDIM + e0 + c4];
            }
            #pragma unroll
            for (int i = 0; i < 6; ++i) {
                int lin = tid + i * 256, c = lin >> 3, c8 = (lin & 7) * 8;
                wv[i] = *(const f16x8*)&Wt[(size_t)c * EDIM + e0 + c8];
            }
        }
        f16x8 a0  = *(const f16x8*)&xs[cur][wave * 16 + lr][lk];
        f16x8 a0b = *(const f16x8*)&xs[cur][wave * 16 + lr][32 + lk];
        #pragma unroll
        for (int nb = 0; nb < 12; ++nb) {
            f16x8 b0 = *(const f16x8*)&wsh[cur][nb * 16 + lr][lk];
            f16x8 b1 = *(const f16x8*)&wsh[cur][nb * 16 + lr][32 + lk];
            acc[nb] = __builtin_amdgcn_mfma_f32_16x16x32_f16(a0,  b0, acc[nb], 0, 0, 0);
            acc[nb] = __builtin_amdgcn_mfma_f32_16x16x32_f16(a0b, b1, acc[nb], 0, 0, 0);
        }
        if (kt < 11) {   // write next tile into alternate buffer
            #pragma unroll
            for (int i = 0; i < 4; ++i) {
                int lin = tid + i * 256, r = lin >> 4, c4 = (lin & 15) * 4;
                f16x4 h;
                h[0] = (_Float16)xv[i][0]; h[1] = (_Float16)xv[i][1];
                h[2] = (_Float16)xv[i][2]; h[3] = (_Float16)xv[i][3];
                *(f16x4*)&xs[cur ^ 1][r][c4] = h;
            }
            #pragma unroll
            for (int i = 0; i < 6; ++i) {
                int lin = tid + i * 256, c = lin >> 3, c8 = (lin & 7) * 8;
                *(f16x8*)&wsh[cur ^ 1][c][c8] = wv[i];
            }
            __syncthreads();
        }
    }

    // store fp16 outputs (C layout: row=(lane>>4)*4+j, col=lane&15)
    #pragma unroll
    for (int nb = 0; nb < 12; ++nb) {
        _Float16* dst = (nb < 4) ? q16 : (nb < 8) ? k16 : v16;
        int lc = (nb & 3) * 16 + lr;
        #pragma unroll
        for (int j = 0; j < 4; ++j)
            dst[(size_t)(m0 + wave * 16 + lrow + j) * HD + lc] = (_Float16)acc[nb][j];
    }

    // per-row K sums (reduce over the 16 lanes sharing a row)
    #pragma unroll
    for (int j = 0; j < 4; ++j) {
        float ks = (acc[4][j] + acc[5][j]) + (acc[6][j] + acc[7][j]);
        ks += __shfl_xor(ks, 1); ks += __shfl_xor(ks, 2);
        ks += __shfl_xor(ks, 4); ks += __shfl_xor(ks, 8);
        if (lr == 0) ksum[m0 + wave * 16 + lrow + j] = ks;
    }

    // per-block LN partials: sum & sumsq for q/k/v
    #pragma unroll
    for (int t3 = 0; t3 < 3; ++t3) {
        float s = 0.f, q = 0.f;
        #pragma unroll
        for (int nb = t3 * 4; nb < t3 * 4 + 4; ++nb)
            #pragma unroll
            for (int j = 0; j < 4; ++j) { float v = acc[nb][j]; s += v; q += v * v; }
        #pragma unroll
        for (int off = 1; off < 64; off <<= 1) {
            s += __shfl_xor(s, off); q += __shfl_xor(q, off);
        }
        if (lane == 0) { red[wave][t3 * 2] = s; red[wave][t3 * 2 + 1] = q; }
    }
    __syncthreads();
    if (tid < 6)
        part[blockIdx.x * 6 + tid] = red[0][tid] + red[1][tid] + red[2][tid] + red[3][tid];
}

// ---------------- kernel 2: reduce per-block partials -> per-batch mean/rstd --------
__global__ __launch_bounds__(64) void stats_reduce(const float* __restrict__ part,
                                                   float* __restrict__ stats) {
    int b = blockIdx.x, a = threadIdx.x;
    if (a < 3) {
        double s = 0.0, q = 0.0;
        for (int i = 0; i < 16; ++i) {
            s += (double)part[(b * 16 + i) * 6 + a * 2];
            q += (double)part[(b * 16 + i) * 6 + a * 2 + 1];
        }
        double mean = s / 65536.0;
        double var  = q / 65536.0 - mean * mean;
        stats[b * 8 + a * 2 + 0] = (float)mean;
        stats[b * 8 + a * 2 + 1] = (float)(1.0 / sqrt(var + 1e-5));
    }
}

// ---------------- kernel 2c: transpose V -> v16t [B][64][1024] ----------------------
__global__ __launch_bounds__(256) void transpose_v(const _Float16* __restrict__ v16,
                                                   _Float16* __restrict__ v16t) {
    __shared__ _Float16 t[64][72];
    int b = blockIdx.x >> 4, s0 = (blockIdx.x & 15) * 64;
    int tid = threadIdx.x;
    for (int i = 0; i < 2; ++i) {
        int lin = tid + i * 256;
        int s = lin >> 3, d8 = (lin & 7) * 8;
        *(f16x8*)&t[s][d8] = *(const f16x8*)&v16[((size_t)b * SEQ + s0 + s) * HD + d8];
    }
    __syncthreads();
    for (int i = 0; i < 2; ++i) {
        int lin = tid + i * 256;
        int d = lin >> 3, s8 = (lin & 7) * 8;
        f16x8 g;
        for (int k = 0; k < 8; ++k) g[k] = t[s8 + k][d];
        *(f16x8*)&v16t[((size_t)b * HD + d) * SEQ + s0 + s8] = g;
    }
}

// ---------------- kernel 3: flash attention, raw fp16 + folded LN -------------------
__global__ __launch_bounds__(256) void attn_kernel(const _Float16* __restrict__ q16,
                                                   const _Float16* __restrict__ k16,
                                                   const _Float16* __restrict__ v16t,
                                                   const float* __restrict__ stats,
                                                   const float* __restrict__ ksum,
                                                   float* __restrict__ out) {
    __shared__ _Float16 ksm[64][72];
    __shared__ _Float16 vsm[64][72];     // [d][kv]
    __shared__ _Float16 psm[4][16][72];  // per-wave, no barrier needed
    // XCD swizzle: all 16 q-tiles of a batch share (blockIdx mod 32) -> same XCD,
    // so K/V stay L2-local (4 batches/XCD = 1 MB of KV in 4 MB L2).
    const int d_ = blockIdx.x;
    const int b = (d_ & 7) * 4 + ((d_ >> 3) & 3), qt = d_ >> 5;
    const int tid = threadIdx.x, wave = tid >> 6, lane = tid & 63;
    const int lr = lane & 15, lk = (lane >> 4) * 8, lrow = (lane >> 4) * 4;
    const float sscale = stats[b * 8 + 1] * stats[b * 8 + 3] * 0.125f;
    const float adjscale = sscale * stats[b * 8 + 0];   // * mq
    const float mv = stats[b * 8 + 4], rv = stats[b * 8 + 5];
    const int q0 = qt * 64 + wave * 16;
    const _Float16* Qb = q16 + ((size_t)b * SEQ + q0) * HD;
    const float* ksb = ksum + b * SEQ;

    f16x8 aq0 = *(const f16x8*)&Qb[(size_t)lr * HD + lk];
    f16x8 aq1 = *(const f16x8*)&Qb[(size_t)lr * HD + 32 + lk];

    f32x4 o[4] = {};
    float mrow[4], lsum[4];
    for (int j = 0; j < 4; ++j) { mrow[j] = -1e30f; lsum[j] = 0.f; }

    for (int kv0 = 0; kv0 < SEQ; kv0 += 64) {
        for (int i = 0; i < 2; ++i) {
            int lin = tid + i * 256;
            int r = lin >> 3, c = (lin & 7) * 8;
            *(f16x8*)&ksm[r][c] = *(const f16x8*)&k16[((size_t)b * SEQ + kv0 + r) * HD + c];
        }
        for (int i = 0; i < 2; ++i) {
            int lin = tid + i * 256;
            int dd = lin >> 3, c = (lin & 7) * 8;
            *(f16x8*)&vsm[dd][c] = *(const f16x8*)&v16t[((size_t)b * HD + dd) * SEQ + kv0 + c];
        }
        __syncthreads();

        // S_raw = Q_raw * K_raw^T
        f32x4 sa[4];
        float adjv[4];
        for (int cb = 0; cb < 4; ++cb) {
            sa[cb] = (f32x4){0.f, 0.f, 0.f, 0.f};
            f16x8 bk0 = *(const f16x8*)&ksm[cb * 16 + lr][lk];
            f16x8 bk1 = *(const f16x8*)&ksm[cb * 16 + lr][32 + lk];
            sa[cb] = __builtin_amdgcn_mfma_f32_16x16x32_f16(aq0, bk0, sa[cb], 0, 0, 0);
            sa[cb] = __builtin_amdgcn_mfma_f32_16x16x32_f16(aq1, bk1, sa[cb], 0, 0, 0);
            adjv[cb] = adjscale * ksb[kv0 + cb * 16 + lr];
        }

        // online softmax (16 lanes per row, shfl-xor tree)
        for (int j = 0; j < 4; ++j) {
            float sv0 = sa[0][j] * sscale - adjv[0];
            float sv1 = sa[1][j] * sscale - adjv[1];
            float sv2 = sa[2][j] * sscale - adjv[2];
            float sv3 = sa[3][j] * sscale - adjv[3];
            float pm = fmaxf(fmaxf(sv0, sv1), fmaxf(sv2, sv3));
            pm = fmaxf(pm, __shfl_xor(pm, 1));
            pm = fmaxf(pm, __shfl_xor(pm, 2));
            pm = fmaxf(pm, __shfl_xor(pm, 4));
            pm = fmaxf(pm, __shfl_xor(pm, 8));
            float mnew  = fmaxf(mrow[j], pm);
            float alpha = __expf(mrow[j] - mnew);
            mrow[j] = mnew;
            float p0 = __expf(sv0 - mnew), p1 = __expf(sv1 - mnew);
            float p2 = __expf(sv2 - mnew), p3 = __expf(sv3 - mnew);
            sa[0][j] = p0; sa[1][j] = p1; sa[2][j] = p2; sa[3][j] = p3;
            float rs = (p0 + p1) + (p2 + p3);
            rs += __shfl_xor(rs, 1); rs += __shfl_xor(rs, 2);
            rs += __shfl_xor(rs, 4); rs += __shfl_xor(rs, 8);
            lsum[j] = lsum[j] * alpha + rs;
            o[0][j] *= alpha; o[1][j] *= alpha; o[2][j] *= alpha; o[3][j] *= alpha;
        }
        for (int cb = 0; cb < 4; ++cb)
            for (int j = 0; j < 4; ++j)
                psm[wave][lrow + j][cb * 16 + lr] = (_Float16)sa[cb][j];
        // same-wave LDS write->read: ordered by lgkmcnt, no barrier

        f16x8 pa0 = *(const f16x8*)&psm[wave][lr][lk];
        f16x8 pa1 = *(const f16x8*)&psm[wave][lr][32 + lk];
        for (int db = 0; db < 4; ++db) {
            f16x8 bv0 = *(const f16x8*)&vsm[db * 16 + lr][lk];
            f16x8 bv1 = *(const f16x8*)&vsm[db * 16 + lr][32 + lk];
            o[db] = __builtin_amdgcn_mfma_f32_16x16x32_f16(pa0, bv0, o[db], 0, 0, 0);
            o[db] = __builtin_amdgcn_mfma_f32_16x16x32_f16(pa1, bv1, o[db], 0, 0, 0);
        }
        __syncthreads();
    }

    for (int j = 0; j < 4; ++j) {
        float inv = 1.f / lsum[j];
        size_t row = (size_t)b * SEQ + q0 + lrow + j;
        for (int db = 0; db < 4; ++db)
            out[row * HD + db * 16 + lr] = rv * (o[db][j] * inv - mv);
    }
}

extern "C" void kernel_launch(void* const* d_in, const int* in_sizes, int n_in,
                              void* d_out, int out_size, void* d_ws, size_t ws_size,
                              hipStream_t stream) {
    const float* x  = (const float*)d_in[0];
    const float* Wq = (const float*)d_in[1];
    const float* Wk = (const float*)d_in[2];
    const float* Wv = (const float*)d_in[3];
    float* out = (float*)d_out;
    char* ws = (char*)d_ws;

    _Float16* Wt   = (_Float16*)ws;                 // 294912 B
    float* stats   = (float*)(ws + 0x50000);        // 1 KB
    float* ksum    = (float*)(ws + 0x51000);        // 128 KB
    float* part    = (float*)(ws + 0x72000);        // 12 KB
    _Float16* q16  = (_Float16*)(ws + 0x100000);    // 4 MiB each
    _Float16* k16  = (_Float16*)(ws + 0x500000);
    _Float16* v16  = (_Float16*)(ws + 0x900000);
    _Float16* v16t = (_Float16*)(ws + 0xD00000);

    pack_w<<<192, 256, 0, stream>>>(Wq, Wk, Wv, Wt);
    proj_kernel<<<MTOT / 64, 256, 0, stream>>>(x, Wt, q16, k16, v16, part, ksum);
    stats_reduce<<<NB, 64, 0, stream>>>(part, stats);
    transpose_v<<<NB * 16, 256, 0, stream>>>(v16, v16t);
    attn_kernel<<<NB * 16, 256, 0, stream>>>(q16, k16, v16t, stats, ksum, out);
}